// Round 1
// baseline (1336.479 us; speedup 1.0000x reference)
//
#include <hip/hip_runtime.h>

typedef unsigned short u16;
typedef __attribute__((ext_vector_type(8))) short bf16x8;
typedef __attribute__((ext_vector_type(4))) float f32x4;

#define M_ROWS 8192
#define N_OUT  14336
#define K_IN   4096

__constant__ float NF4_TAB[16] = {
    -1.0f, -0.6961928009986877f, -0.5250730514526367f, -0.39491748809814453f,
    -0.28444138169288635f, -0.18477343022823334f, -0.09105003625154495f, 0.0f,
    0.07958029955625534f, 0.16093020141124725f, 0.24611230194568634f,
    0.33791524171829224f, 0.44070982933044434f, 0.5626170039176941f,
    0.7229568362236023f, 1.0f};

// fp32 -> bf16 round-to-nearest-even (bit-level, no header dependency)
static __device__ __forceinline__ u16 f2bf(float f) {
  union { float f; unsigned u; } v;
  v.f = f;
  unsigned u = v.u;
  unsigned r = (u + 0x7fffu + ((u >> 16) & 1u)) >> 16;
  return (u16)r;
}

// async global->LDS, 16B per lane; lds pointer must be wave-uniform
static __device__ __forceinline__ void async_load16(const void* g, void* l) {
  __builtin_amdgcn_global_load_lds(
      (const __attribute__((address_space(1))) void*)g,
      (__attribute__((address_space(3))) void*)l, 16, 0, 0);
}

// ---------------------------------------------------------------------------
// Dequant W: each thread handles 4 packed int32 (4 bytes worth of codes)
// -> 8 bf16 outputs (one 16B store). 8 outputs never cross a 64-block.
// ---------------------------------------------------------------------------
__global__ __launch_bounds__(256) void dequant_w_kernel(
    const int* __restrict__ wp, const float* __restrict__ wa,
    u16* __restrict__ wout) {
  int t = blockIdx.x * 256 + threadIdx.x;   // 7,340,032 threads
  const int4 p = reinterpret_cast<const int4*>(wp)[t];
  float am = wa[t >> 3];                    // block = (t*8)/64
  int v[4] = {p.x, p.y, p.z, p.w};
  union { u16 us[8]; int4 v4; } o;
#pragma unroll
  for (int j = 0; j < 4; ++j) {
    o.us[2 * j]     = f2bf(NF4_TAB[(v[j] >> 4) & 15] * am);  // hi nibble first
    o.us[2 * j + 1] = f2bf(NF4_TAB[v[j] & 15] * am);
  }
  reinterpret_cast<int4*>(wout)[t] = o.v4;
}

// ---------------------------------------------------------------------------
// Convert X fp32 -> bf16, 8 elements/thread
// ---------------------------------------------------------------------------
__global__ __launch_bounds__(256) void convert_x_kernel(
    const float* __restrict__ x, u16* __restrict__ xb) {
  int t = blockIdx.x * 256 + threadIdx.x;   // 4,194,304 threads
  const float4 a = reinterpret_cast<const float4*>(x)[2 * t];
  const float4 b = reinterpret_cast<const float4*>(x)[2 * t + 1];
  union { u16 us[8]; int4 v4; } o;
  o.us[0] = f2bf(a.x); o.us[1] = f2bf(a.y);
  o.us[2] = f2bf(a.z); o.us[3] = f2bf(a.w);
  o.us[4] = f2bf(b.x); o.us[5] = f2bf(b.y);
  o.us[6] = f2bf(b.z); o.us[7] = f2bf(b.w);
  reinterpret_cast<int4*>(xb)[t] = o.v4;
}

// ---------------------------------------------------------------------------
// NT GEMM: C[M][N] = A[M][K] * B[N][K]^T + bias (m97 structure: 128x128 tile,
// BK=32, 4 waves in 2x2, 16x16x32 bf16 MFMA, global_load_lds staging)
// ---------------------------------------------------------------------------
__global__ __launch_bounds__(256) void gemm_nf4_kernel(
    const u16* __restrict__ A,   // [M][K] bf16
    const u16* __restrict__ B,   // [N][K] bf16
    float* __restrict__ C,       // [M][N] fp32
    const int* __restrict__ bp,  // packed bias codes
    const float* __restrict__ ba) {
  constexpr int N = N_OUT, K = K_IN;
  constexpr int NT = N / 128;    // 112 n-tiles

  __shared__ u16 sA[128 * 32];
  __shared__ u16 sB[128 * 32];

  const int tid = threadIdx.x;
  const int wid = tid >> 6;
  const int lane = tid & 63;
  const int r = lane & 15;       // fragment row (output dim)
  const int kq = lane >> 4;      // k quadrant (8 bf16 each)
  const int wr = wid >> 1, wc = wid & 1;

  // bijective XCD-aware swizzle (gridDim.x = 7168, divisible by 8)
  int bid = blockIdx.x;
  int cpx = gridDim.x >> 3;
  int wg = (bid & 7) * cpx + (bid >> 3);
  int mt = wg / NT, nt = wg % NT;
  long m0 = (long)mt * 128, n0 = (long)nt * 128;

  const u16* gA = A + m0 * K;
  const u16* gB = B + n0 * K;

  f32x4 acc[4][4] = {};

  for (int kt = 0; kt < K; kt += 32) {
    // stage 128x32 bf16 A-tile and B-tile: 512 chunks of 16B each,
    // 256 threads x 2 iterations; LDS dest linear in chunk order
#pragma unroll
    for (int i = 0; i < 2; ++i) {
      int c = i * 256 + tid;
      int row = c >> 2, kc = c & 3;
      const u16* ga = gA + (long)row * K + kt + kc * 8;
      const u16* gb = gB + (long)row * K + kt + kc * 8;
      int ldsoff = (i * 256 + wid * 64) * 8;  // wave-uniform base (ushorts)
      async_load16(ga, &sA[ldsoff]);
      async_load16(gb, &sB[ldsoff]);
    }
    __syncthreads();  // drains vmcnt(0) before barrier (compiler-inserted)

    bf16x8 aF[4], bF[4];
#pragma unroll
    for (int m = 0; m < 4; ++m)
      aF[m] = *(const bf16x8*)&sA[(wr * 64 + m * 16 + r) * 32 + kq * 8];
#pragma unroll
    for (int n = 0; n < 4; ++n)
      bF[n] = *(const bf16x8*)&sB[(wc * 64 + n * 16 + r) * 32 + kq * 8];

#pragma unroll
    for (int m = 0; m < 4; ++m)
#pragma unroll
      for (int n = 0; n < 4; ++n)
        acc[m][n] = __builtin_amdgcn_mfma_f32_16x16x32_bf16(
            aF[m], bF[n], acc[m][n], 0, 0, 0);
    __syncthreads();  // compute done before next-tile overwrite
  }

  // epilogue: fused NF4 bias dequant + store
  // C/D layout (16x16x32): col = lane&15, row = (lane>>4)*4 + reg
  float bias[4];
#pragma unroll
  for (int n = 0; n < 4; ++n) {
    int col = (int)n0 + wc * 64 + n * 16 + r;
    int byte = bp[col >> 1];
    int code = (col & 1) ? (byte & 15) : ((byte >> 4) & 15);
    bias[n] = NF4_TAB[code] * ba[col >> 6];
  }
#pragma unroll
  for (int m = 0; m < 4; ++m) {
    long row0 = m0 + wr * 64 + m * 16 + kq * 4;
#pragma unroll
    for (int n = 0; n < 4; ++n) {
      long col = n0 + wc * 64 + n * 16 + r;
#pragma unroll
      for (int j = 0; j < 4; ++j)
        C[(row0 + j) * N + col] = acc[m][n][j] + bias[n];
    }
  }
}

extern "C" void kernel_launch(void* const* d_in, const int* in_sizes, int n_in,
                              void* d_out, int out_size, void* d_ws,
                              size_t ws_size, hipStream_t stream) {
  const float* x  = (const float*)d_in[0];  // [8192,4096] fp32
  const int* wp   = (const int*)d_in[1];    // [N*K/2] packed codes
  const float* wa = (const float*)d_in[2];  // [N*K/64] absmax
  const int* bp   = (const int*)d_in[3];    // [N/2] packed bias codes
  const float* ba = (const float*)d_in[4];  // [N/64] bias absmax
  float* out = (float*)d_out;

  u16* Wb = (u16*)d_ws;                          // [N][K] bf16: 117,440,512 B
  u16* Xb = Wb + (size_t)N_OUT * K_IN;           // [M][K] bf16:  67,108,864 B

  // W dequant: 29,360,128 packed / 4 per thread = 7,340,032 threads
  dequant_w_kernel<<<28672, 256, 0, stream>>>(wp, wa, Wb);
  // X convert: 33,554,432 floats / 8 per thread = 4,194,304 threads
  convert_x_kernel<<<16384, 256, 0, stream>>>(x, Xb);
  // GEMM: 64 m-tiles x 112 n-tiles = 7168 blocks
  gemm_nf4_kernel<<<7168, 256, 0, stream>>>(Xb, Wb, out, bp, ba);
}

// Round 2
// 904.765 us; speedup vs baseline: 1.4772x; 1.4772x over previous
//
#include <hip/hip_runtime.h>

typedef unsigned short u16;
typedef __attribute__((ext_vector_type(8))) short bf16x8;
typedef __attribute__((ext_vector_type(4))) float f32x4;

#define M_ROWS 8192
#define N_OUT  14336
#define K_IN   4096
#define NTILE  64   // K_IN / 64

__constant__ float NF4_TAB[16] = {
    -1.0f, -0.6961928009986877f, -0.5250730514526367f, -0.39491748809814453f,
    -0.28444138169288635f, -0.18477343022823334f, -0.09105003625154495f, 0.0f,
    0.07958029955625534f, 0.16093020141124725f, 0.24611230194568634f,
    0.33791524171829224f, 0.44070982933044434f, 0.5626170039176941f,
    0.7229568362236023f, 1.0f};

static __device__ __forceinline__ u16 f2bf(float f) {
  union { float f; unsigned u; } v;
  v.f = f;
  unsigned u = v.u;
  unsigned r = (u + 0x7fffu + ((u >> 16) & 1u)) >> 16;
  return (u16)r;
}

static __device__ __forceinline__ void async_load16(const void* g, void* l) {
  __builtin_amdgcn_global_load_lds(
      (const __attribute__((address_space(1))) void*)g,
      (__attribute__((address_space(3))) void*)l, 16, 0, 0);
}

// ---------------------------------------------------------------------------
// Dequant W: 4 packed int32 / thread -> 8 bf16 (one 16B store)
// ---------------------------------------------------------------------------
__global__ __launch_bounds__(256) void dequant_w_kernel(
    const int* __restrict__ wp, const float* __restrict__ wa,
    u16* __restrict__ wout) {
  int t = blockIdx.x * 256 + threadIdx.x;
  const int4 p = reinterpret_cast<const int4*>(wp)[t];
  float am = wa[t >> 3];
  int v[4] = {p.x, p.y, p.z, p.w};
  union { u16 us[8]; int4 v4; } o;
#pragma unroll
  for (int j = 0; j < 4; ++j) {
    o.us[2 * j]     = f2bf(NF4_TAB[(v[j] >> 4) & 15] * am);
    o.us[2 * j + 1] = f2bf(NF4_TAB[v[j] & 15] * am);
  }
  reinterpret_cast<int4*>(wout)[t] = o.v4;
}

// ---------------------------------------------------------------------------
// Convert X fp32 -> bf16, 8 elements/thread
// ---------------------------------------------------------------------------
__global__ __launch_bounds__(256) void convert_x_kernel(
    const float* __restrict__ x, u16* __restrict__ xb) {
  int t = blockIdx.x * 256 + threadIdx.x;
  const float4 a = reinterpret_cast<const float4*>(x)[2 * t];
  const float4 b = reinterpret_cast<const float4*>(x)[2 * t + 1];
  union { u16 us[8]; int4 v4; } o;
  o.us[0] = f2bf(a.x); o.us[1] = f2bf(a.y);
  o.us[2] = f2bf(a.z); o.us[3] = f2bf(a.w);
  o.us[4] = f2bf(b.x); o.us[5] = f2bf(b.y);
  o.us[6] = f2bf(b.z); o.us[7] = f2bf(b.w);
  reinterpret_cast<int4*>(xb)[t] = o.v4;
}

// ---------------------------------------------------------------------------
// 256x256x64 8-phase pipelined NT GEMM (plain-HIP port of the m201 template)
// A[M][K], B[N][K] bf16; C[M][N] fp32 + NF4 bias.
// LDS: 2 buffers x (A 256x64 + B 256x64) bf16 = 128 KiB (dynamic).
// Swizzle: 16B chunk c' = c ^ (row&7), applied via pre-swizzled global src
// (linear gload_lds dest) + swizzled ds_read offsets (same involution).
// ---------------------------------------------------------------------------
__global__ __launch_bounds__(512, 2) void gemm_nf4_256(
    const u16* __restrict__ A, const u16* __restrict__ B,
    float* __restrict__ C, const int* __restrict__ bp,
    const float* __restrict__ ba) {
  constexpr int K = K_IN, N = N_OUT;
  extern __shared__ u16 smem[];
  u16* sA = smem;            // [2][256][64]
  u16* sB = smem + 32768;    // [2][256][64]

  const int tid = threadIdx.x;
  const int w = tid >> 6, lane = tid & 63;
  const int r = lane & 15, kq = lane >> 4;
  const int wr = w >> 2, wc = w & 3;       // 2 x 4 wave grid

  // bijective XCD swizzle (1792 blocks, 1792 % 8 == 0)
  int bid = blockIdx.x;
  int cpx = gridDim.x >> 3;
  int wg = (bid & 7) * cpx + (bid >> 3);
  int mt = wg / (N / 256), nt = wg % (N / 256);
  const size_t m0 = (size_t)mt * 256, n0 = (size_t)nt * 256;

  const u16* gA = A + m0 * K;
  const u16* gB = B + n0 * K;

  // read-side swizzled chunk offsets (u16 units) for k-half 0/1
  const int cswz0 = ((kq) ^ (r & 7)) * 8;
  const int cswz1 = ((4 + kq) ^ (r & 7)) * 8;
  // stage-side per-lane global chunk (involution partner of the above)
  const int cg = ((lane & 7) ^ (lane >> 3)) * 8;
  const int jlane = lane >> 3;

  f32x4 acc[8][4] = {};
  bf16x8 aF[4][2], bF[4][2];

#define FENCE() asm volatile("" ::: "memory")
#define BAR() do { __builtin_amdgcn_s_barrier(); FENCE(); } while (0)
#define LGKM0() asm volatile("s_waitcnt lgkmcnt(0)" ::: "memory")
#define VM(n) asm volatile("s_waitcnt vmcnt(" #n ")" ::: "memory")

#define STAGE_A(u, mq) do {                                                  \
    int P_ = (u) & 1;                                                        \
    _Pragma("unroll")                                                        \
    for (int i_ = 0; i_ < 2; ++i_) {                                         \
      int j0_ = (i_ * 8 + w) * 8;                                            \
      int R0_ = (mq) * 64 + ((j0_ >> 6) << 7) + (j0_ & 63);                  \
      int R_ = R0_ + jlane;                                                  \
      async_load16(gA + (size_t)R_ * K + (u) * 64 + cg,                      \
                   sA + P_ * 16384 + R0_ * 64);                              \
    } } while (0)

#define STAGE_B(u, nq) do {                                                  \
    int P_ = (u) & 1;                                                        \
    _Pragma("unroll")                                                        \
    for (int i_ = 0; i_ < 2; ++i_) {                                         \
      int j0_ = (i_ * 8 + w) * 8;                                            \
      int R0_ = (nq) * 32 + ((j0_ >> 5) << 6) + (j0_ & 31);                  \
      int R_ = R0_ + jlane;                                                  \
      async_load16(gB + (size_t)R_ * K + (u) * 64 + cg,                      \
                   sB + P_ * 16384 + R0_ * 64);                              \
    } } while (0)

#define READ_A(P, mq) do {                                                   \
    const u16* ba_ = sA + (P) * 16384 + (wr * 128 + (mq) * 64 + r) * 64;     \
    _Pragma("unroll")                                                        \
    for (int m_ = 0; m_ < 4; ++m_) {                                         \
      aF[m_][0] = *(const bf16x8*)(ba_ + m_ * 1024 + cswz0);                 \
      aF[m_][1] = *(const bf16x8*)(ba_ + m_ * 1024 + cswz1);                 \
    } } while (0)

#define READ_B(P, nq) do {                                                   \
    const u16* bb_ = sB + (P) * 16384 + (wc * 64 + (nq) * 32 + r) * 64;      \
    _Pragma("unroll")                                                        \
    for (int n_ = 0; n_ < 2; ++n_) {                                         \
      bF[(nq) * 2 + n_][0] = *(const bf16x8*)(bb_ + n_ * 1024 + cswz0);      \
      bF[(nq) * 2 + n_][1] = *(const bf16x8*)(bb_ + n_ * 1024 + cswz1);      \
    } } while (0)

#define MFMA_Q(mq, nq) do {                                                  \
    __builtin_amdgcn_s_setprio(1);                                           \
    _Pragma("unroll")                                                        \
    for (int m_ = 0; m_ < 4; ++m_)                                           \
      _Pragma("unroll")                                                      \
      for (int n_ = 0; n_ < 2; ++n_) {                                       \
        acc[(mq) * 4 + m_][(nq) * 2 + n_] =                                  \
            __builtin_amdgcn_mfma_f32_16x16x32_bf16(                         \
                aF[m_][0], bF[(nq) * 2 + n_][0],                             \
                acc[(mq) * 4 + m_][(nq) * 2 + n_], 0, 0, 0);                 \
        acc[(mq) * 4 + m_][(nq) * 2 + n_] =                                  \
            __builtin_amdgcn_mfma_f32_16x16x32_bf16(                         \
                aF[m_][1], bF[(nq) * 2 + n_][1],                             \
                acc[(mq) * 4 + m_][(nq) * 2 + n_], 0, 0, 0);                 \
      }                                                                      \
    __builtin_amdgcn_s_setprio(0);                                           \
  } while (0)

  // TILE: 4 phases; stages: p1 -> (s+1).A1, p2 -> (s+2).A0, p3 -> (s+2).B0,
  // p4 -> (s+2).B1. Every staged region's last read was >=1 barrier before
  // the stage issue (race-free); vmcnt(6) at p4 lands all of tile s+1.
#define TILE(s, P, DO_P1, DO_P234, VMSTMT) do {                              \
    READ_A(P, 0); READ_B(P, 0);                                              \
    if (DO_P1) STAGE_A((s) + 1, 1);                                          \
    BAR(); LGKM0(); MFMA_Q(0, 0); BAR();                                     \
    READ_B(P, 1);                                                            \
    if (DO_P234) STAGE_A((s) + 2, 0);                                        \
    BAR(); LGKM0(); MFMA_Q(0, 1); BAR();                                     \
    READ_A(P, 1);                                                            \
    if (DO_P234) STAGE_B((s) + 2, 0);                                        \
    BAR(); LGKM0(); MFMA_Q(1, 0); BAR();                                     \
    if (DO_P234) STAGE_B((s) + 2, 1);                                        \
    BAR(); MFMA_Q(1, 1);                                                     \
    VMSTMT; BAR();                                                           \
  } while (0)

  // prologue: tile0 fully + tile1 {A0,B0,B1}; tile1.A1 comes at s=0 p1
  STAGE_A(0, 0); STAGE_B(0, 0); STAGE_B(0, 1); STAGE_A(0, 1);
  STAGE_A(1, 0); STAGE_B(1, 0); STAGE_B(1, 1);
  VM(6); BAR();

  for (int s = 0; s < NTILE - 2; s += 2) {
    TILE(s, 0, 1, 1, VM(6));
    TILE((s) + 1, 1, 1, 1, VM(6));
  }
  TILE(NTILE - 2, 0, 1, 0, VM(0));   // stage 63.A1 only; drain
  TILE(NTILE - 1, 1, 0, 0, (void)0);

  // epilogue: fused NF4 bias + store (C/D: col=lane&15, row=(lane>>4)*4+j)
  float bias[4];
#pragma unroll
  for (int ni = 0; ni < 4; ++ni) {
    int col = (int)n0 + wc * 64 + ni * 16 + r;
    int byte = bp[col >> 1];
    int code = (col & 1) ? (byte & 15) : ((byte >> 4) & 15);
    bias[ni] = NF4_TAB[code] * ba[col >> 6];
  }
#pragma unroll
  for (int mi = 0; mi < 8; ++mi) {
    size_t row0 = m0 + wr * 128 + mi * 16 + kq * 4;
#pragma unroll
    for (int ni = 0; ni < 4; ++ni) {
      size_t col = n0 + wc * 64 + ni * 16 + r;
#pragma unroll
      for (int j = 0; j < 4; ++j)
        C[(row0 + j) * N + col] = acc[mi][ni][j] + bias[ni];
    }
  }
#undef TILE
#undef MFMA_Q
#undef READ_B
#undef READ_A
#undef STAGE_B
#undef STAGE_A
#undef VM
#undef LGKM0
#undef BAR
#undef FENCE
}

extern "C" void kernel_launch(void* const* d_in, const int* in_sizes, int n_in,
                              void* d_out, int out_size, void* d_ws,
                              size_t ws_size, hipStream_t stream) {
  const float* x  = (const float*)d_in[0];
  const int* wp   = (const int*)d_in[1];
  const float* wa = (const float*)d_in[2];
  const int* bp   = (const int*)d_in[3];
  const float* ba = (const float*)d_in[4];
  float* out = (float*)d_out;

  u16* Wb = (u16*)d_ws;                     // [N][K] bf16
  u16* Xb = Wb + (size_t)N_OUT * K_IN;      // [M][K] bf16

  dequant_w_kernel<<<28672, 256, 0, stream>>>(wp, wa, Wb);
  convert_x_kernel<<<16384, 256, 0, stream>>>(x, Xb);

  hipFuncSetAttribute(reinterpret_cast<const void*>(gemm_nf4_256),
                      hipFuncAttributeMaxDynamicSharedMemorySize, 131072);
  // 32 m-tiles x 56 n-tiles
  gemm_nf4_256<<<1792, 512, 131072, stream>>>(Xb, Wb, out, bp, ba);
}

// Round 3
// 853.542 us; speedup vs baseline: 1.5658x; 1.0600x over previous
//
#include <hip/hip_runtime.h>

typedef unsigned short u16;
typedef __attribute__((ext_vector_type(8))) short bf16x8;
typedef __attribute__((ext_vector_type(4))) float f32x4;
typedef __attribute__((ext_vector_type(4))) int i32x4;

#define M_ROWS 8192
#define N_OUT  14336
#define K_IN   4096
#define NTILE  64   // K_IN / 64

__constant__ float NF4_TAB[16] = {
    -1.0f, -0.6961928009986877f, -0.5250730514526367f, -0.39491748809814453f,
    -0.28444138169288635f, -0.18477343022823334f, -0.09105003625154495f, 0.0f,
    0.07958029955625534f, 0.16093020141124725f, 0.24611230194568634f,
    0.33791524171829224f, 0.44070982933044434f, 0.5626170039176941f,
    0.7229568362236023f, 1.0f};

static __device__ __forceinline__ u16 f2bf(float f) {
  union { float f; unsigned u; } v;
  v.f = f;
  unsigned u = v.u;
  unsigned r = (u + 0x7fffu + ((u >> 16) & 1u)) >> 16;
  return (u16)r;
}

static __device__ __forceinline__ void async_load16(const void* g, void* l) {
  __builtin_amdgcn_global_load_lds(
      (const __attribute__((address_space(1))) void*)g,
      (__attribute__((address_space(3))) void*)l, 16, 0, 0);
}

// ---------------------------------------------------------------------------
// Dequant W: 4 packed int32 / thread -> 8 bf16 (one 16B store)
// nt-load the packed stream (single use); normal store Wb (re-read by GEMM,
// want L3 residency).
// ---------------------------------------------------------------------------
__global__ __launch_bounds__(256) void dequant_w_kernel(
    const int* __restrict__ wp, const float* __restrict__ wa,
    u16* __restrict__ wout) {
  int t = blockIdx.x * 256 + threadIdx.x;
  const i32x4 p = __builtin_nontemporal_load(
      reinterpret_cast<const i32x4*>(wp) + t);
  float am = wa[t >> 3];
  int v[4] = {p.x, p.y, p.z, p.w};
  union { u16 us[8]; i32x4 v4; } o;
#pragma unroll
  for (int j = 0; j < 4; ++j) {
    o.us[2 * j]     = f2bf(NF4_TAB[(v[j] >> 4) & 15] * am);
    o.us[2 * j + 1] = f2bf(NF4_TAB[v[j] & 15] * am);
  }
  reinterpret_cast<i32x4*>(wout)[t] = o.v4;
}

// ---------------------------------------------------------------------------
// Convert X fp32 -> bf16, 8 elements/thread; nt-load x (single use)
// ---------------------------------------------------------------------------
__global__ __launch_bounds__(256) void convert_x_kernel(
    const float* __restrict__ x, u16* __restrict__ xb) {
  int t = blockIdx.x * 256 + threadIdx.x;
  const f32x4 a = __builtin_nontemporal_load(
      reinterpret_cast<const f32x4*>(x) + 2 * t);
  const f32x4 b = __builtin_nontemporal_load(
      reinterpret_cast<const f32x4*>(x) + 2 * t + 1);
  union { u16 us[8]; i32x4 v4; } o;
  o.us[0] = f2bf(a.x); o.us[1] = f2bf(a.y);
  o.us[2] = f2bf(a.z); o.us[3] = f2bf(a.w);
  o.us[4] = f2bf(b.x); o.us[5] = f2bf(b.y);
  o.us[6] = f2bf(b.z); o.us[7] = f2bf(b.w);
  reinterpret_cast<i32x4*>(xb)[t] = o.v4;
}

// ---------------------------------------------------------------------------
// 256x256x64 8-phase pipelined NT GEMM (m201 template in plain HIP)
// A[M][K], B[N][K] bf16; C[M][N] fp32 + NF4 bias, non-temporal C stores.
// LDS: 2 buffers x (A 256x64 + B 256x64) bf16 = 128 KiB (dynamic).
// Swizzle: 16B chunk c' = c ^ (row&7) via pre-swizzled global src (linear
// gload_lds dest) + swizzled ds_read offsets (same involution).
// ---------------------------------------------------------------------------
__global__ __launch_bounds__(512, 2) void gemm_nf4_256(
    const u16* __restrict__ A, const u16* __restrict__ B,
    float* __restrict__ C, const int* __restrict__ bp,
    const float* __restrict__ ba) {
  constexpr int K = K_IN, N = N_OUT;
  extern __shared__ u16 smem[];
  u16* sA = smem;            // [2][256][64]
  u16* sB = smem + 32768;    // [2][256][64]

  const int tid = threadIdx.x;
  const int w = tid >> 6, lane = tid & 63;
  const int r = lane & 15, kq = lane >> 4;
  const int wr = w >> 2, wc = w & 3;       // 2 x 4 wave grid

  // bijective XCD swizzle (1792 % 8 == 0): contiguous 224-wg chunk per XCD
  int bid = blockIdx.x;
  int cpx = gridDim.x >> 3;
  int wg = (bid & 7) * cpx + (bid >> 3);
  // mt-inner-8 supertile: 56 nt-cols x 32 mt-rows in 4 groups of 8 m-rows;
  // concurrent blocks on an XCD then share few B-panels (L2-hot).
  int grp = wg / 448;                  // 448 = 56*8
  int rem = wg - grp * 448;
  int nt = rem >> 3;
  int mt = grp * 8 + (rem & 7);
  const size_t m0 = (size_t)mt * 256, n0 = (size_t)nt * 256;

  const u16* gA = A + m0 * K;
  const u16* gB = B + n0 * K;

  // read-side swizzled chunk offsets (u16 units) for k-half 0/1
  const int cswz0 = ((kq) ^ (r & 7)) * 8;
  const int cswz1 = ((4 + kq) ^ (r & 7)) * 8;
  // stage-side per-lane global chunk (involution partner of the above)
  const int cg = ((lane & 7) ^ (lane >> 3)) * 8;
  const int jlane = lane >> 3;

  f32x4 acc[8][4] = {};
  bf16x8 aF[4][2], bF[4][2];

#define FENCE() asm volatile("" ::: "memory")
#define BAR() do { __builtin_amdgcn_s_barrier(); FENCE(); } while (0)
#define LGKM0() asm volatile("s_waitcnt lgkmcnt(0)" ::: "memory")
#define LGKM8() asm volatile("s_waitcnt lgkmcnt(8)" ::: "memory")
#define VM(n) asm volatile("s_waitcnt vmcnt(" #n ")" ::: "memory")

#define STAGE_A(u, mq) do {                                                  \
    int P_ = (u) & 1;                                                        \
    _Pragma("unroll")                                                        \
    for (int i_ = 0; i_ < 2; ++i_) {                                         \
      int j0_ = (i_ * 8 + w) * 8;                                            \
      int R0_ = (mq) * 64 + ((j0_ >> 6) << 7) + (j0_ & 63);                  \
      int R_ = R0_ + jlane;                                                  \
      async_load16(gA + (size_t)R_ * K + (u) * 64 + cg,                      \
                   sA + P_ * 16384 + R0_ * 64);                              \
    } } while (0)

#define STAGE_B(u, nq) do {                                                  \
    int P_ = (u) & 1;                                                        \
    _Pragma("unroll")                                                        \
    for (int i_ = 0; i_ < 2; ++i_) {                                         \
      int j0_ = (i_ * 8 + w) * 8;                                            \
      int R0_ = (nq) * 32 + ((j0_ >> 5) << 6) + (j0_ & 31);                  \
      int R_ = R0_ + jlane;                                                  \
      async_load16(gB + (size_t)R_ * K + (u) * 64 + cg,                      \
                   sB + P_ * 16384 + R0_ * 64);                              \
    } } while (0)

#define READ_A(P, mq) do {                                                   \
    const u16* ba_ = sA + (P) * 16384 + (wr * 128 + (mq) * 64 + r) * 64;     \
    _Pragma("unroll")                                                        \
    for (int m_ = 0; m_ < 4; ++m_) {                                         \
      aF[m_][0] = *(const bf16x8*)(ba_ + m_ * 1024 + cswz0);                 \
      aF[m_][1] = *(const bf16x8*)(ba_ + m_ * 1024 + cswz1);                 \
    } } while (0)

#define READ_B(P, nq) do {                                                   \
    const u16* bb_ = sB + (P) * 16384 + (wc * 64 + (nq) * 32 + r) * 64;      \
    _Pragma("unroll")                                                        \
    for (int n_ = 0; n_ < 2; ++n_) {                                         \
      bF[(nq) * 2 + n_][0] = *(const bf16x8*)(bb_ + n_ * 1024 + cswz0);      \
      bF[(nq) * 2 + n_][1] = *(const bf16x8*)(bb_ + n_ * 1024 + cswz1);      \
    } } while (0)

#define MFMA_Q(mq, nq) do {                                                  \
    __builtin_amdgcn_s_setprio(1);                                           \
    _Pragma("unroll")                                                        \
    for (int m_ = 0; m_ < 4; ++m_)                                           \
      _Pragma("unroll")                                                      \
      for (int n_ = 0; n_ < 2; ++n_) {                                       \
        acc[(mq) * 4 + m_][(nq) * 2 + n_] =                                  \
            __builtin_amdgcn_mfma_f32_16x16x32_bf16(                         \
                aF[m_][0], bF[(nq) * 2 + n_][0],                             \
                acc[(mq) * 4 + m_][(nq) * 2 + n_], 0, 0, 0);                 \
        acc[(mq) * 4 + m_][(nq) * 2 + n_] =                                  \
            __builtin_amdgcn_mfma_f32_16x16x32_bf16(                         \
                aF[m_][1], bF[(nq) * 2 + n_][1],                             \
                acc[(mq) * 4 + m_][(nq) * 2 + n_], 0, 0, 0);                 \
      }                                                                      \
    __builtin_amdgcn_s_setprio(0);                                           \
  } while (0)

  // TILE: 4 phases; stages: p1 -> (s+1).A1, p2 -> (s+2).A0, p3 -> (s+2).B0,
  // p4 -> (s+2).B1. Every staged region's last read was >=1 barrier before
  // the stage issue (race-free); vmcnt(6) at p4 lands all of tile s+1.
#define TILE(s, P, DO_P1, DO_P234, VMSTMT) do {                              \
    READ_A(P, 0); READ_B(P, 0);                                              \
    if (DO_P1) STAGE_A((s) + 1, 1);                                          \
    LGKM8();                                                                 \
    BAR(); LGKM0(); MFMA_Q(0, 0); BAR();                                     \
    READ_B(P, 1);                                                            \
    if (DO_P234) STAGE_A((s) + 2, 0);                                        \
    BAR(); LGKM0(); MFMA_Q(0, 1); BAR();                                     \
    READ_A(P, 1);                                                            \
    if (DO_P234) STAGE_B((s) + 2, 0);                                        \
    BAR(); LGKM0(); MFMA_Q(1, 0); BAR();                                     \
    if (DO_P234) STAGE_B((s) + 2, 1);                                        \
    BAR(); MFMA_Q(1, 1);                                                     \
    VMSTMT; BAR();                                                           \
  } while (0)

  // prologue: tile0 fully + tile1 {A0,B0,B1}; tile1.A1 comes at s=0 p1
  STAGE_A(0, 0); STAGE_B(0, 0); STAGE_B(0, 1); STAGE_A(0, 1);
  STAGE_A(1, 0); STAGE_B(1, 0); STAGE_B(1, 1);
  VM(6); BAR();

  for (int s = 0; s < NTILE - 2; s += 2) {
    TILE(s, 0, 1, 1, VM(6));
    TILE((s) + 1, 1, 1, 1, VM(6));
  }
  TILE(NTILE - 2, 0, 1, 0, VM(0));   // stage 63.A1 only; drain
  TILE(NTILE - 1, 1, 0, 0, (void)0);

  // epilogue: fused NF4 bias + non-temporal C stores
  // (C/D: col=lane&15, row=(lane>>4)*4+j)
  float bias[4];
#pragma unroll
  for (int ni = 0; ni < 4; ++ni) {
    int col = (int)n0 + wc * 64 + ni * 16 + r;
    int byte = bp[col >> 1];
    int code = (col & 1) ? (byte & 15) : ((byte >> 4) & 15);
    bias[ni] = NF4_TAB[code] * ba[col >> 6];
  }
#pragma unroll
  for (int mi = 0; mi < 8; ++mi) {
    size_t row0 = m0 + wr * 128 + mi * 16 + kq * 4;
#pragma unroll
    for (int ni = 0; ni < 4; ++ni) {
      size_t col = n0 + wc * 64 + ni * 16 + r;
#pragma unroll
      for (int j = 0; j < 4; ++j)
        __builtin_nontemporal_store(acc[mi][ni][j] + bias[ni],
                                    &C[(row0 + j) * N + col]);
    }
  }
#undef TILE
#undef MFMA_Q
#undef READ_B
#undef READ_A
#undef STAGE_B
#undef STAGE_A
#undef VM
#undef LGKM8
#undef LGKM0
#undef BAR
#undef FENCE
}

extern "C" void kernel_launch(void* const* d_in, const int* in_sizes, int n_in,
                              void* d_out, int out_size, void* d_ws,
                              size_t ws_size, hipStream_t stream) {
  const float* x  = (const float*)d_in[0];
  const int* wp   = (const int*)d_in[1];
  const float* wa = (const float*)d_in[2];
  const int* bp   = (const int*)d_in[3];
  const float* ba = (const float*)d_in[4];
  float* out = (float*)d_out;

  u16* Wb = (u16*)d_ws;                     // [N][K] bf16
  u16* Xb = Wb + (size_t)N_OUT * K_IN;      // [M][K] bf16

  dequant_w_kernel<<<28672, 256, 0, stream>>>(wp, wa, Wb);
  convert_x_kernel<<<16384, 256, 0, stream>>>(x, Xb);

  hipFuncSetAttribute(reinterpret_cast<const void*>(gemm_nf4_256),
                      hipFuncAttributeMaxDynamicSharedMemorySize, 131072);
  // 32 m-tiles x 56 n-tiles
  gemm_nf4_256<<<1792, 512, 131072, stream>>>(Xb, Wb, out, bp, ba);
}